// Round 18
// baseline (186.240 us; speedup 1.0000x reference)
//
#include <hip/hip_runtime.h>
#include <math.h>

#define NN 50000
#define EE 800000
#define ETOT 850000   // EE + NN self loops
#define INF 128
#define DD 64
#define CAP 64        // per-node slots; P(deg>64) ~ e^-44 for 1+Poisson(16)
#define NB_NODE ((NN + 63) / 64)               // 782 blocks, 64 nodes each
#define NB_EDGE ((ETOT + 255) / 256)           // 3321
#define XP 65         // x-stage pitch [128][65]: stage-write & read conflict-free
#define TP 67         // transpose-out pitch [64][67]: 2/bank (free)

// ---------- helpers ----------
__device__ __forceinline__ float wsum64(float v) {
#pragma unroll
    for (int m = 1; m < 64; m <<= 1) v += __shfl_xor(v, m, 64);
    return v;
}
__device__ __forceinline__ float rlf(float v, int k) {   // k compile-time
    return __int_as_float(__builtin_amdgcn_readlane(__float_as_int(v), k));
}

// Minkowski inner (slow path only): full row per lane, divergent
__device__ __forceinline__ float mink_full(const float* __restrict__ ox,
                                           int j, float xnv) {
    const float4* ojp = (const float4*)(ox + (size_t)(unsigned)j * DD);
    float4 oj[16];
#pragma unroll
    for (int q = 0; q < 16; ++q) oj[q] = ojp[q];
    float p0 = 0.f, p1 = 0.f, p2 = 0.f, p3 = 0.f;
#pragma unroll
    for (int q = 0; q < 16; ++q) {
        p0 = fmaf(rlf(xnv, 4 * q + 0), oj[q].x, p0);
        p1 = fmaf(rlf(xnv, 4 * q + 1), oj[q].y, p1);
        p2 = fmaf(rlf(xnv, 4 * q + 2), oj[q].z, p2);
        p3 = fmaf(rlf(xnv, 4 * q + 3), oj[q].w, p3);
    }
    return (p0 + p1 + p2 + p3) - 2.f * rlf(xnv, 0) * oj[0].x;
}

// quarter GEMM: NC cols starting at c0 (c0 in SGPR -> W via s_load)
template<int NC>
__device__ __forceinline__ void gemm_q(const float* __restrict__ S,
                                       const float* __restrict__ W,
                                       int c0, int lane, float* acc) {
#pragma unroll 4
    for (int k = 0; k < INF; ++k) {
        float xk = S[k * XP + lane];
        const float* wr = W + (size_t)k * 63 + c0;
#pragma unroll
        for (int c = 0; c < NC; ++c) acc[c] = fmaf(xk, wr[c], acc[c]);
    }
}

// ---------- K1: node transform, 4 threads/node (col-quarters), LDS x ----
__global__ __launch_bounds__(256) void k_node(
    const float* __restrict__ x, const float* __restrict__ W,
    const float* __restrict__ b, const float* __restrict__ att,
    float* __restrict__ ox, float* __restrict__ ai, float2* __restrict__ snd)
{
    __shared__ float S[INF * XP];      // 33280 B: x-stage, later out-transpose
    __shared__ float PP0[256], PP1[256], PP2[256];

    const int tid  = threadIdx.x;
    const int lane = tid & 63;                       // node slot
    const int h    = __builtin_amdgcn_readfirstlane(tid >> 6);  // quarter, SGPR
    const int c0   = 16 * h;                         // uniform (SGPR)
    const int n0   = blockIdx.x * 64;
    const int n    = n0 + lane;

    // ---- stage x: 64 nodes x 128 k, coalesced scalar loads ----
    for (int r = 0; r < 32; ++r) {
        int e = r * 256 + tid;
        int node = e >> 7, k = e & 127;
        int gn = min(n0 + node, NN - 1);
        S[k * XP + node] = x[(size_t)gn * INF + k];
    }
    __syncthreads();

    // ---- quarter GEMM: acc[16] (h=3 uses 15) ----
    float acc[16];
#pragma unroll
    for (int c = 0; c < 16; ++c) acc[c] = 0.f;
    if (h < 3) gemm_q<16>(S, W, c0, lane, acc);
    else       gemm_q<15>(S, W, c0, lane, acc);
    const int nc = (h == 3) ? 15 : 16;

    // ---- epilogue: bias + partial sum-of-squares, combine via LDS ----
    float ssp = 0.f;
#pragma unroll
    for (int c = 0; c < 16; ++c) {
        if (c < nc) {
            acc[c] += b[c0 + c];
            ssp = fmaf(acc[c], acc[c], ssp);
        }
    }
    PP0[tid] = ssp;
    __syncthreads();                   // also: S (x data) dead after this
    float ss = PP0[lane] + PP0[64 + lane] + PP0[128 + lane] + PP0[192 + lane];

    float t   = sqrtf(ss + 1.0f);             // C = 1
    float nrm = sqrtf(ss + 1e-15f);
    float d0  = acoshf(fmaxf(t, 1.0f + 1e-6f));
    float scl = d0 / nrm;

    float aip = 0.f, ajp = 0.f;
#pragma unroll
    for (int c = 0; c < 16; ++c) {
        if (c < nc) {
            float lxv = scl * acc[c];
            aip = fmaf(lxv, att[1 + c0 + c], aip);
            ajp = fmaf(lxv, att[DD + 1 + c0 + c], ajp);
        }
    }
    PP1[tid] = aip; PP2[tid] = ajp;

    // write my quarter into transpose area T[node][d] (pitch TP)
#pragma unroll
    for (int c = 0; c < 16; ++c)
        if (c < nc) S[lane * TP + 1 + c0 + c] = acc[c];
    if (h == 0) S[lane * TP + 0] = t;
    __syncthreads();

    if (h == 0 && n < NN) {
        float aiv = PP1[lane] + PP1[64 + lane] + PP1[128 + lane] + PP1[192 + lane];
        float ajv = PP2[lane] + PP2[64 + lane] + PP2[128 + lane] + PP2[192 + lane];
        ai[n] = aiv;
        snd[n] = make_float2(ajv, scl);
    }

    // ---- coalesced ox write-out: 64 nodes x 64 dims ----
    for (int r = 0; r < 16; ++r) {
        int e = r * 256 + tid;
        int node = e >> 6, d = e & 63;
        if (n0 + node < NN)
            ox[(size_t)(n0 + node) * DD + d] = S[node * TP + d];
    }
}

// ---------- K2: edge bucket placement ----------
__global__ __launch_bounds__(256) void k_place(
    const int* __restrict__ ei0, const int* __restrict__ ei1,
    int* __restrict__ cnt, int* __restrict__ colPad)
{
    int e = blockIdx.x * 256 + threadIdx.x;
    if (e >= ETOT) return;
    int i, j;
    if (e < EE) { i = ei0[e]; j = ei1[e]; }
    else        { i = e - EE; j = i; }
    int pos = atomicAdd(&cnt[i], 1);
    if (pos < CAP) colPad[(size_t)i * CAP + pos] = j;
}

// ---------- K3: fused edge phase + epilogue: one wave per node ----------
__global__ __launch_bounds__(256) void k_fused(
    const int* __restrict__ cnt, const int* __restrict__ colPad,
    const float* __restrict__ ox, const float* __restrict__ ai,
    const float2* __restrict__ snd, float* __restrict__ y)
{
    const int lane = threadIdx.x & 63;
    const int wid  = threadIdx.x >> 6;
    const int n = blockIdx.x * 4 + wid;
    if (n >= NN) return;

    const int base = n * CAP;
    int deg = cnt[n];
    if (deg > CAP) deg = CAP;   // never triggers (safety)
    const float aii = ai[n];

    if (deg <= 32) {
        // ==== FAST PATH: 16-lane cooperative rows, fragments in registers ====
        const int s = lane & 15;     // dim segment: dims 4s..4s+3
        const int g = lane >> 4;     // group: edge slot per step

        float4 xf = *(const float4*)(ox + (size_t)n * DD + 4 * s);
        if (s == 0) xf.x = -xf.x;    // Minkowski sign fold

        // per-edge bookkeeping (lane-per-edge), then bpermute to steps
        const int  ecl = min(lane, deg - 1);
        const int  jreg = colPad[base + ecl];
        const float2 sv = snd[jreg];

        const int nst = (deg + 3) >> 2;   // 1..8, wave-uniform
        int js[8]; float ajs[8], scs[8], pt[8], e1[8], w[8];
        float4 fr[8];

#pragma unroll
        for (int t = 0; t < 8; ++t) {
            if (t < nst) {
                int e = 4 * t + g;
                int ec = min(e, deg - 1);
                js[t]  = __shfl(jreg, ec, 64);
                ajs[t] = __shfl(sv.x, ec, 64);
                scs[t] = __shfl(sv.y, ec, 64);
            }
        }
        // coalesced row loads (4 rows x 256B per step), all in flight
#pragma unroll
        for (int t = 0; t < 8; ++t) {
            if (t < nst)
                fr[t] = *(const float4*)(ox + (size_t)(unsigned)js[t] * DD + 4 * s);
        }
        // dot4 + 16-lane reduce per step
#pragma unroll
        for (int t = 0; t < 8; ++t) {
            if (t < nst) {
                float p = xf.x * fr[t].x;
                p = fmaf(xf.y, fr[t].y, p);
                p = fmaf(xf.z, fr[t].z, p);
                p = fmaf(xf.w, fr[t].w, p);
                p += __shfl_xor(p, 1, 64);
                p += __shfl_xor(p, 2, 64);
                p += __shfl_xor(p, 4, 64);
                p += __shfl_xor(p, 8, 64);
                pt[t] = p;               // inner_e on all 16 lanes of group
            }
        }
        // softmax 1 (no max-sub: sq <= ~45 safe in f32)
        float s1p = 0.f;
#pragma unroll
        for (int t = 0; t < 8; ++t) {
            if (t < nst) {
                int e = 4 * t + g;
                float arg = fmaxf(-pt[t], 1.0f + 1e-6f);
                float dd0 = acoshf(arg);
                float v = (e < deg) ? expf(dd0 * dd0) : 0.f;
                e1[t] = v;
                s1p += v;
            }
        }
        s1p += __shfl_xor(s1p, 16, 64);
        s1p += __shfl_xor(s1p, 32, 64);
        const float inv1 = 1.f / (s1p + 1e-16f);
        // softmax 2 (|al| = O(1), no max-sub)
        float s2p = 0.f;
#pragma unroll
        for (int t = 0; t < 8; ++t) {
            if (t < nst) {
                int e = 4 * t + g;
                float al = (aii + ajs[t]) * e1[t] * inv1;
                al = (al >= 0.f) ? al : 0.2f * al;
                float v = (e < deg) ? expf(al) : 0.f;
                w[t] = v;
                s2p += v;
            }
        }
        s2p += __shfl_xor(s2p, 16, 64);
        s2p += __shfl_xor(s2p, 32, 64);
        const float inv2 = 1.f / (s2p + 1e-16f);
        // PV from retained fragments (scl_j folded)
        float4 a4 = make_float4(0.f, 0.f, 0.f, 0.f);
#pragma unroll
        for (int t = 0; t < 8; ++t) {
            if (t < nst) {
                float wt = w[t] * inv2 * scs[t];
                a4.x = fmaf(wt, fr[t].x, a4.x);
                a4.y = fmaf(wt, fr[t].y, a4.y);
                a4.z = fmaf(wt, fr[t].z, a4.z);
                a4.w = fmaf(wt, fr[t].w, a4.w);
            }
        }
        // cross-group combine (4 partial PVs)
        a4.x += __shfl_xor(a4.x, 16, 64); a4.x += __shfl_xor(a4.x, 32, 64);
        a4.y += __shfl_xor(a4.y, 16, 64); a4.y += __shfl_xor(a4.y, 32, 64);
        a4.z += __shfl_xor(a4.z, 16, 64); a4.z += __shfl_xor(a4.z, 32, 64);
        a4.w += __shfl_xor(a4.w, 16, 64); a4.w += __shfl_xor(a4.w, 32, 64);

        // epilogue: relu + exp map on 4-dim fragments
        float u0 = (s == 0) ? 0.f : fmaxf(a4.x, 0.f);
        float u1 = fmaxf(a4.y, 0.f);
        float u2 = fmaxf(a4.z, 0.f);
        float u3 = fmaxf(a4.w, 0.f);
        float ssl = u0 * u0 + u1 * u1 + u2 * u2 + u3 * u3;
        ssl += __shfl_xor(ssl, 1, 64);
        ssl += __shfl_xor(ssl, 2, 64);
        ssl += __shfl_xor(ssl, 4, 64);
        ssl += __shfl_xor(ssl, 8, 64);
        float un = sqrtf(ssl + 1e-15f);
        float sc = sinhf(un) / un;
        float time = sqrtf(sc * sc * ssl + 1.0f);
        if (g == 0) {
            float4 o;
            o.x = (s == 0) ? time : sc * u0;
            o.y = sc * u1;
            o.z = sc * u2;
            o.w = sc * u3;
            *(float4*)(y + (size_t)n * DD + 4 * s) = o;
        }
    } else {
        // ==== SLOW PATH (32 < deg <= 64): lane-per-edge, ~15 nodes total ====
        const float xnv = ox[(size_t)n * DD + lane];
        const bool act = lane < deg;
        const int  ecl = min(lane, deg - 1);
        const int  jreg = colPad[base + ecl];
        const float2 sv = snd[jreg];

        float inner = mink_full(ox, jreg, xnv);
        float arg = fmaxf(-inner, 1.0f + 1e-6f);
        float dd0 = acoshf(arg);
        float sq  = dd0 * dd0;

        float e1 = act ? expf(sq) : 0.f;
        float s1 = wsum64(e1) + 1e-16f;
        float al = (aii + sv.x) * e1 / s1;
        al = (al >= 0.f) ? al : 0.2f * al;
        float p2 = act ? expf(al) : 0.f;
        float s2 = wsum64(p2);
        float w2 = p2 / (s2 + 1e-16f) * sv.y;

        float acc = 0.f;
        int k = 0;
        for (; k + 8 <= deg; k += 8) {
            float w0 = __shfl(w2, k + 0, 64), w1 = __shfl(w2, k + 1, 64);
            float w2b = __shfl(w2, k + 2, 64), w3 = __shfl(w2, k + 3, 64);
            float w4 = __shfl(w2, k + 4, 64), w5 = __shfl(w2, k + 5, 64);
            float w6 = __shfl(w2, k + 6, 64), w7 = __shfl(w2, k + 7, 64);
            int j0 = __shfl(jreg, k + 0, 64), j1 = __shfl(jreg, k + 1, 64);
            int j2 = __shfl(jreg, k + 2, 64), j3 = __shfl(jreg, k + 3, 64);
            int j4 = __shfl(jreg, k + 4, 64), j5 = __shfl(jreg, k + 5, 64);
            int j6 = __shfl(jreg, k + 6, 64), j7 = __shfl(jreg, k + 7, 64);
            float v0 = ox[(size_t)j0 * DD + lane], v1 = ox[(size_t)j1 * DD + lane];
            float v2 = ox[(size_t)j2 * DD + lane], v3 = ox[(size_t)j3 * DD + lane];
            float v4 = ox[(size_t)j4 * DD + lane], v5 = ox[(size_t)j5 * DD + lane];
            float v6 = ox[(size_t)j6 * DD + lane], v7 = ox[(size_t)j7 * DD + lane];
            acc = fmaf(w0, v0, acc);  acc = fmaf(w1, v1, acc);
            acc = fmaf(w2b, v2, acc); acc = fmaf(w3, v3, acc);
            acc = fmaf(w4, v4, acc);  acc = fmaf(w5, v5, acc);
            acc = fmaf(w6, v6, acc);  acc = fmaf(w7, v7, acc);
        }
        for (; k < deg; ++k) {
            float w = __shfl(w2, k, 64);
            int   j = __shfl(jreg, k, 64);
            acc = fmaf(w, ox[(size_t)j * DD + lane], acc);
        }

        float usp = (lane == 0) ? 0.f : fmaxf(acc, 0.f);
        float ss = wsum64(usp * usp);
        float un = sqrtf(ss + 1e-15f);
        float sc = sinhf(un) / un;
        float sp = sc * usp;
        float time = sqrtf(sc * sc * ss + 1.0f);
        y[(size_t)n * DD + lane] = (lane == 0) ? time : sp;
    }
}

extern "C" void kernel_launch(void* const* d_in, const int* in_sizes, int n_in,
                              void* d_out, int out_size, void* d_ws, size_t ws_size,
                              hipStream_t stream) {
    const float* x   = (const float*)d_in[0];
    const float* W   = (const float*)d_in[1];
    const float* b   = (const float*)d_in[2];
    const float* att = (const float*)d_in[3];
    const int*   ei  = (const int*)d_in[4];
    const int* ei0 = ei;
    const int* ei1 = ei + EE;
    float* out = (float*)d_out;

    // workspace layout (~26.5 MB)
    float*  ws  = (float*)d_ws;
    float*  ox  = ws;                                 // N*64
    float*  ai  = ox + (size_t)NN * DD;               // N
    float2* snd = (float2*)(ai + NN);                 // N float2 (8B aligned)
    int*    cnt    = (int*)(snd + NN);                // N
    int*    colPad = cnt + NN;                        // N*CAP

    hipMemsetAsync(cnt, 0, sizeof(int) * NN, stream);

    // standalone kernels: clean per-kernel attribution
    k_place<<<NB_EDGE, 256, 0, stream>>>(ei0, ei1, cnt, colPad);
    k_node<<<NB_NODE, 256, 0, stream>>>(x, W, b, att, ox, ai, snd);
    k_fused<<<(NN + 3) / 4, 256, 0, stream>>>(cnt, colPad, ox, ai, snd, out);
}

// Round 19
// 133.495 us; speedup vs baseline: 1.3951x; 1.3951x over previous
//
#include <hip/hip_runtime.h>
#include <math.h>

#define NN 50000
#define EE 800000
#define ETOT 850000   // EE + NN self loops
#define INF 128
#define DD 64
#define CAP 64        // per-node slots; P(deg>64) ~ e^-44 for 1+Poisson(16)
#define NB_NODE ((NN + 63) / 64)               // 782 blocks, 64 nodes each
#define NB_EDGE ((ETOT + 255) / 256)           // 3321
#define KCH 64        // k-chunk: halves LDS vs R17
#define XP 65         // x-stage pitch: stage-write & read conflict-free
#define TP 67         // transpose-out pitch: 2/bank (free)

// ---------- helpers ----------
__device__ __forceinline__ float wsum64(float v) {
#pragma unroll
    for (int m = 1; m < 64; m <<= 1) v += __shfl_xor(v, m, 64);
    return v;
}
__device__ __forceinline__ float rlf(float v, int k) {   // k compile-time
    return __int_as_float(__builtin_amdgcn_readlane(__float_as_int(v), k));
}

// Minkowski inner: full row per lane (divergent but parallel — empirically
// beats shuffle-coalesced variants, see R5/R18 post-mortems)
__device__ __forceinline__ float mink_full(const float* __restrict__ ox,
                                           int j, float xnv) {
    const float4* ojp = (const float4*)(ox + (size_t)(unsigned)j * DD);
    float4 oj[16];
#pragma unroll
    for (int q = 0; q < 16; ++q) oj[q] = ojp[q];
    float p0 = 0.f, p1 = 0.f, p2 = 0.f, p3 = 0.f;
#pragma unroll
    for (int q = 0; q < 16; ++q) {
        p0 = fmaf(rlf(xnv, 4 * q + 0), oj[q].x, p0);
        p1 = fmaf(rlf(xnv, 4 * q + 1), oj[q].y, p1);
        p2 = fmaf(rlf(xnv, 4 * q + 2), oj[q].z, p2);
        p3 = fmaf(rlf(xnv, 4 * q + 3), oj[q].w, p3);
    }
    return (p0 + p1 + p2 + p3) - 2.f * rlf(xnv, 0) * oj[0].x;
}

// quarter GEMM over one k-chunk: NC cols at c0 (c0 uniform -> W via s_load)
template<int NC>
__device__ __forceinline__ void gemm_q(const float* __restrict__ S,
                                       const float* __restrict__ W,
                                       int k0, int c0, int lane, float* acc) {
#pragma unroll 4
    for (int k = 0; k < KCH; ++k) {
        float xk = S[k * XP + lane];
        const float* wr = W + (size_t)(k0 + k) * 63 + c0;
#pragma unroll
        for (int c = 0; c < NC; ++c) acc[c] = fmaf(xk, wr[c], acc[c]);
    }
}

// ---------- K1: node transform (4 threads/node, chunked LDS x)
//              + edge bucket placement (extra blocks of same grid) ----------
__global__ __launch_bounds__(256) void k_node_place(
    const float* __restrict__ x, const float* __restrict__ W,
    const float* __restrict__ b, const float* __restrict__ att,
    const int* __restrict__ ei0, const int* __restrict__ ei1,
    float* __restrict__ ox, float* __restrict__ ai, float2* __restrict__ snd,
    int* __restrict__ cnt, int* __restrict__ colPad)
{
    __shared__ float S[DD * TP];       // 17152 B: x-stage chunk / out-transpose
    __shared__ float PP0[256], PP1[256], PP2[256];

    if (blockIdx.x >= NB_NODE) {
        // ---- edge path: one-pass bucket placement (overlaps node GEMM) ----
        int e = (blockIdx.x - NB_NODE) * 256 + threadIdx.x;
        if (e < ETOT) {
            int i, j;
            if (e < EE) { i = ei0[e]; j = ei1[e]; }
            else        { i = e - EE; j = i; }
            int pos = atomicAdd(&cnt[i], 1);
            if (pos < CAP) colPad[(size_t)i * CAP + pos] = j;
        }
        return;
    }

    const int tid  = threadIdx.x;
    const int lane = tid & 63;                       // node slot
    const int h    = __builtin_amdgcn_readfirstlane(tid >> 6);  // quarter, SGPR
    const int c0   = 16 * h;                         // uniform (SGPR)
    const int n0   = blockIdx.x * 64;
    const int n    = n0 + lane;

    float acc[16];
#pragma unroll
    for (int c = 0; c < 16; ++c) acc[c] = 0.f;

    // ---- chunked: stage 64 nodes x 64 k, then quarter-GEMM; x2 ----
    for (int k0 = 0; k0 < INF; k0 += KCH) {
        __syncthreads();               // WAR: previous chunk's reads done
        for (int r = 0; r < 16; ++r) {
            int e = r * 256 + tid;
            int node = e >> 6, k = e & 63;
            int gn = min(n0 + node, NN - 1);
            S[k * XP + node] = x[(size_t)gn * INF + k0 + k];
        }
        __syncthreads();
        if (h < 3) gemm_q<16>(S, W, k0, c0, lane, acc);
        else       gemm_q<15>(S, W, k0, c0, lane, acc);
    }
    const int nc = (h == 3) ? 15 : 16;

    // ---- epilogue: bias + partial sum-of-squares, combine via LDS ----
    float ssp = 0.f;
#pragma unroll
    for (int c = 0; c < 16; ++c) {
        if (c < nc) {
            acc[c] += b[c0 + c];
            ssp = fmaf(acc[c], acc[c], ssp);
        }
    }
    PP0[tid] = ssp;
    __syncthreads();                   // also: S (x data) dead after this
    float ss = PP0[lane] + PP0[64 + lane] + PP0[128 + lane] + PP0[192 + lane];

    float t   = sqrtf(ss + 1.0f);             // C = 1
    float nrm = sqrtf(ss + 1e-15f);
    float d0  = acoshf(fmaxf(t, 1.0f + 1e-6f));
    float scl = d0 / nrm;

    float aip = 0.f, ajp = 0.f;
#pragma unroll
    for (int c = 0; c < 16; ++c) {
        if (c < nc) {
            float lxv = scl * acc[c];
            aip = fmaf(lxv, att[1 + c0 + c], aip);
            ajp = fmaf(lxv, att[DD + 1 + c0 + c], ajp);
        }
    }
    PP1[tid] = aip; PP2[tid] = ajp;

    // write my quarter into transpose area T[node][d] (pitch TP)
#pragma unroll
    for (int c = 0; c < 16; ++c)
        if (c < nc) S[lane * TP + 1 + c0 + c] = acc[c];
    if (h == 0) S[lane * TP + 0] = t;
    __syncthreads();

    if (h == 0 && n < NN) {
        float aiv = PP1[lane] + PP1[64 + lane] + PP1[128 + lane] + PP1[192 + lane];
        float ajv = PP2[lane] + PP2[64 + lane] + PP2[128 + lane] + PP2[192 + lane];
        ai[n] = aiv;
        snd[n] = make_float2(ajv, scl);
    }

    // ---- coalesced ox write-out: 64 nodes x 64 dims ----
    for (int r = 0; r < 16; ++r) {
        int e = r * 256 + tid;
        int node = e >> 6, d = e & 63;
        if (n0 + node < NN)
            ox[(size_t)(n0 + node) * DD + d] = S[node * TP + d];
    }
}

// ---------- K2: fused edge phase + epilogue: one wave per node (R17) ----------
__global__ __launch_bounds__(256) void k_fused(
    const int* __restrict__ cnt, const int* __restrict__ colPad,
    const float* __restrict__ ox, const float* __restrict__ ai,
    const float2* __restrict__ snd, float* __restrict__ y)
{
    const int lane = threadIdx.x & 63;
    const int wid  = threadIdx.x >> 6;
    const int n = blockIdx.x * 4 + wid;
    if (n >= NN) return;

    const int base = n * CAP;
    int deg = cnt[n];
    if (deg > CAP) deg = CAP;   // never triggers (safety)
    const float aii = ai[n];
    const float xnv = ox[(size_t)n * DD + lane];

    // ---- lane-per-edge fast path ----
    const bool act = lane < deg;
    const int  ecl = min(lane, deg - 1);
    const int  jreg = colPad[base + ecl];
    const float2 sv = snd[jreg];               // (aj, scl) 8B gather

    float inner = mink_full(ox, jreg, xnv);
    float arg = fmaxf(-inner, 1.0f + 1e-6f);
    float dd0 = acoshf(arg);
    float sq  = dd0 * dd0;

    // softmax 1 without max-subtraction: sq <= ~45 -> exp safe in f32
    float e1 = act ? expf(sq) : 0.f;
    float s1 = wsum64(e1) + 1e-16f;
    float al = (aii + sv.x) * e1 / s1;
    al = (al >= 0.f) ? al : 0.2f * al;
    // softmax 2 without max-subtraction: |al| = O(1)
    float p2 = act ? expf(al) : 0.f;
    float s2 = wsum64(p2);
    float w2 = p2 / (s2 + 1e-16f) * sv.y;      // fold scl_j

    // ---- sweep C: coalesced broadcast re-gather, 8 in flight ----
    float acc = 0.f;
    int k = 0;
    for (; k + 8 <= deg; k += 8) {
        float w0 = __shfl(w2, k + 0, 64), w1 = __shfl(w2, k + 1, 64);
        float w2b = __shfl(w2, k + 2, 64), w3 = __shfl(w2, k + 3, 64);
        float w4 = __shfl(w2, k + 4, 64), w5 = __shfl(w2, k + 5, 64);
        float w6 = __shfl(w2, k + 6, 64), w7 = __shfl(w2, k + 7, 64);
        int j0 = __shfl(jreg, k + 0, 64), j1 = __shfl(jreg, k + 1, 64);
        int j2 = __shfl(jreg, k + 2, 64), j3 = __shfl(jreg, k + 3, 64);
        int j4 = __shfl(jreg, k + 4, 64), j5 = __shfl(jreg, k + 5, 64);
        int j6 = __shfl(jreg, k + 6, 64), j7 = __shfl(jreg, k + 7, 64);
        float v0 = ox[(size_t)j0 * DD + lane], v1 = ox[(size_t)j1 * DD + lane];
        float v2 = ox[(size_t)j2 * DD + lane], v3 = ox[(size_t)j3 * DD + lane];
        float v4 = ox[(size_t)j4 * DD + lane], v5 = ox[(size_t)j5 * DD + lane];
        float v6 = ox[(size_t)j6 * DD + lane], v7 = ox[(size_t)j7 * DD + lane];
        acc = fmaf(w0, v0, acc);  acc = fmaf(w1, v1, acc);
        acc = fmaf(w2b, v2, acc); acc = fmaf(w3, v3, acc);
        acc = fmaf(w4, v4, acc);  acc = fmaf(w5, v5, acc);
        acc = fmaf(w6, v6, acc);  acc = fmaf(w7, v7, acc);
    }
    for (; k < deg; ++k) {
        float w = __shfl(w2, k, 64);
        int   j = __shfl(jreg, k, 64);
        acc = fmaf(w, ox[(size_t)j * DD + lane], acc);
    }

    // ---- fused epilogue: relu + exp map ----
    float usp = (lane == 0) ? 0.f : fmaxf(acc, 0.f);
    float ss = wsum64(usp * usp);
    float un = sqrtf(ss + 1e-15f);
    float sc = sinhf(un) / un;
    float sp = sc * usp;
    float time = sqrtf(sc * sc * ss + 1.0f);
    y[(size_t)n * DD + lane] = (lane == 0) ? time : sp;
}

extern "C" void kernel_launch(void* const* d_in, const int* in_sizes, int n_in,
                              void* d_out, int out_size, void* d_ws, size_t ws_size,
                              hipStream_t stream) {
    const float* x   = (const float*)d_in[0];
    const float* W   = (const float*)d_in[1];
    const float* b   = (const float*)d_in[2];
    const float* att = (const float*)d_in[3];
    const int*   ei  = (const int*)d_in[4];
    const int* ei0 = ei;
    const int* ei1 = ei + EE;
    float* out = (float*)d_out;

    // workspace layout (~26.5 MB)
    float*  ws  = (float*)d_ws;
    float*  ox  = ws;                                 // N*64
    float*  ai  = ox + (size_t)NN * DD;               // N
    float2* snd = (float2*)(ai + NN);                 // N float2 (8B aligned)
    int*    cnt    = (int*)(snd + NN);                // N
    int*    colPad = cnt + NN;                        // N*CAP

    hipMemsetAsync(cnt, 0, sizeof(int) * NN, stream);

    // node transform + edge bucket placement (one grid, node blocks first)
    k_node_place<<<NB_NODE + NB_EDGE, 256, 0, stream>>>(
        x, W, b, att, ei0, ei1, ox, ai, snd, cnt, colPad);

    // fused edge phase + epilogue
    k_fused<<<(NN + 3) / 4, 256, 0, stream>>>(cnt, colPad, ox, ai, snd, out);
}